// Round 2
// baseline (53.091 us; speedup 1.0000x reference)
//
#include <hip/hip_runtime.h>
#include <hip/hip_cooperative_groups.h>

namespace cg = cooperative_groups;

// Problem geometry (from reference): x is (B, H, T) = (4096, 1024, 26) f32.
// Only x[b, j, 6:12] for j in [0,26) is used:
//   q[b, j, k] = x[b, j, 6+k],  k in [0,6)
// cost(b,j) = 1/denom via Sherman-Morrison on M = 2I + 0.5 c c^T:
//   denom = 0.5*sum(L^2 s^2) - 0.125*(sum(L s c))^2 / (1 + 0.25*sum(c^2))
// Output = scalar sum over all (b, j).
//
// Single cooperative launch: per-block partials -> grid sync -> block 0 reduces.

#define T_DIM 26
#define H_DIM 1024
#define TASKS_PER_B 26
#define BLK 256

__global__ void cost_fused_kernel(const float* __restrict__ x,
                                  double* __restrict__ partial,
                                  float* __restrict__ out,
                                  int ntasks) {
    __shared__ double red[BLK / 64];

    const int t = blockIdx.x * BLK + threadIdx.x;
    double acc = 0.0;
    if (t < ntasks) {
        const int b = t / TASKS_PER_B;
        const int j = t - b * TASKS_PER_B;
        const float* q = x + (size_t)b * (H_DIM * T_DIM) + (size_t)j * T_DIM + 6;
        // q is 8-byte aligned (byte offset 104*j + 24): three float2 loads.
        const float2 q01 = *(const float2*)(q + 0);
        const float2 q23 = *(const float2*)(q + 2);
        const float2 q45 = *(const float2*)(q + 4);
        const float qa[6] = {q01.x, q01.y, q23.x, q23.y, q45.x, q45.y};

        float cq = 0.0f, sL2s2 = 0.0f, sLsc = 0.0f, sc2 = 0.0f;
#pragma unroll
        for (int i = 0; i < 6; ++i) {
            const float Li = (float)(i + 1) * 0.1f + 0.3f;  // matches reference f32 L
            cq += qa[i];
            const float s = sinf(cq);
            const float c = cosf(cq);
            sL2s2 += (Li * s) * (Li * s);
            sLsc  += Li * s * c;
            sc2   += c * c;
        }
        const double denom = 0.5 * (double)sL2s2
                           - 0.125 * (double)sLsc * (double)sLsc
                                   / (1.0 + 0.25 * (double)sc2);
        acc = 1.0 / denom;
    }

    // wave-64 butterfly reduce
#pragma unroll
    for (int off = 32; off >= 1; off >>= 1)
        acc += __shfl_down(acc, off, 64);

    const int lane = threadIdx.x & 63;
    const int wid  = threadIdx.x >> 6;
    if (lane == 0) red[wid] = acc;
    __syncthreads();
    if (threadIdx.x == 0) {
        double s = 0.0;
#pragma unroll
        for (int w = 0; w < BLK / 64; ++w) s += red[w];
        partial[blockIdx.x] = s;
    }

    cg::this_grid().sync();

    // block 0 reduces all block partials (fixed tree order -> deterministic)
    if (blockIdx.x == 0) {
        const int nblocks = gridDim.x;
        double a = 0.0;
        for (int i = threadIdx.x; i < nblocks; i += BLK) a += partial[i];
#pragma unroll
        for (int off = 32; off >= 1; off >>= 1)
            a += __shfl_down(a, off, 64);
        if (lane == 0) red[wid] = a;
        __syncthreads();
        if (threadIdx.x == 0) {
            double s = 0.0;
#pragma unroll
            for (int w = 0; w < BLK / 64; ++w) s += red[w];
            out[0] = (float)s;
        }
    }
}

extern "C" void kernel_launch(void* const* d_in, const int* in_sizes, int n_in,
                              void* d_out, int out_size, void* d_ws, size_t ws_size,
                              hipStream_t stream) {
    const float* x = (const float*)d_in[0];
    // d_in[1] = cond (unused), d_in[2] = time (gives B)
    const int B = in_sizes[2];
    int ntasks = B * TASKS_PER_B;

    int nblocks = (ntasks + BLK - 1) / BLK;   // 416 for B=4096
    double* partial = (double*)d_ws;
    float* out = (float*)d_out;

    void* args[] = {(void*)&x, (void*)&partial, (void*)&out, (void*)&ntasks};
    hipLaunchCooperativeKernel((void*)cost_fused_kernel,
                               dim3(nblocks), dim3(BLK), args, 0, stream);
}

// Round 3
// 11.669 us; speedup vs baseline: 4.5495x; 4.5495x over previous
//
#include <hip/hip_runtime.h>

// Problem geometry (from reference): x is (B, H, T) = (4096, 1024, 26) f32.
// Only x[b, j, 6:12] for j in [0,26) is used:
//   q[b, j, k] = x[b, j, 6+k],  k in [0,6)
// cost(b,j) = 1/denom via Sherman-Morrison on M = 2I + 0.5 c c^T:
//   denom = 0.5*sum(L^2 s^2) - 0.125*(sum(L s c))^2 / (1 + 0.25*sum(c^2))
// Output = scalar sum over all (b, j).
//
// R2 post-mortem: cooperative launch + grid.sync cost +40us under graph
// capture -> reverted to two plain dispatches (R1 structure, 12.7us) and
// kept the f32 sincos + float2 load improvements (kernel-1 compute cut).

#define T_DIM 26
#define H_DIM 1024
#define TASKS_PER_B 26
#define BLK 256

__global__ void cost_partial_kernel(const float* __restrict__ x,
                                    double* __restrict__ partial,
                                    int ntasks) {
    __shared__ double red[BLK / 64];

    const int t = blockIdx.x * BLK + threadIdx.x;
    double acc = 0.0;
    if (t < ntasks) {
        const int b = t / TASKS_PER_B;
        const int j = t - b * TASKS_PER_B;
        const float* q = x + (size_t)b * (H_DIM * T_DIM) + (size_t)j * T_DIM + 6;
        // q is 8-byte aligned (byte offset 104*j + 24): three float2 loads.
        const float2 q01 = *(const float2*)(q + 0);
        const float2 q23 = *(const float2*)(q + 2);
        const float2 q45 = *(const float2*)(q + 4);
        const float qa[6] = {q01.x, q01.y, q23.x, q23.y, q45.x, q45.y};

        float cq = 0.0f, sL2s2 = 0.0f, sLsc = 0.0f, sc2 = 0.0f;
#pragma unroll
        for (int i = 0; i < 6; ++i) {
            const float Li = (float)(i + 1) * 0.1f + 0.3f;  // matches reference f32 L
            cq += qa[i];
            float s, c;
            __sincosf(cq, &s, &c);
            sL2s2 += (Li * s) * (Li * s);
            sLsc  += Li * s * c;
            sc2   += c * c;
        }
        // Final combine + reciprocal in f64: protects against cancellation
        // when denom is small (cost spikes), costs ~nothing per thread.
        const double denom = 0.5 * (double)sL2s2
                           - 0.125 * (double)sLsc * (double)sLsc
                                   / (1.0 + 0.25 * (double)sc2);
        acc = 1.0 / denom;
    }

    // wave-64 butterfly reduce
#pragma unroll
    for (int off = 32; off >= 1; off >>= 1)
        acc += __shfl_down(acc, off, 64);

    const int lane = threadIdx.x & 63;
    const int wid  = threadIdx.x >> 6;
    if (lane == 0) red[wid] = acc;
    __syncthreads();
    if (threadIdx.x == 0) {
        double s = 0.0;
#pragma unroll
        for (int w = 0; w < BLK / 64; ++w) s += red[w];
        partial[blockIdx.x] = s;
    }
}

__global__ void cost_final_kernel(const double* __restrict__ partial,
                                  int n,
                                  float* __restrict__ out) {
    __shared__ double red[BLK / 64];
    double acc = 0.0;
    for (int i = threadIdx.x; i < n; i += BLK) acc += partial[i];
#pragma unroll
    for (int off = 32; off >= 1; off >>= 1)
        acc += __shfl_down(acc, off, 64);
    const int lane = threadIdx.x & 63;
    const int wid  = threadIdx.x >> 6;
    if (lane == 0) red[wid] = acc;
    __syncthreads();
    if (threadIdx.x == 0) {
        double s = 0.0;
#pragma unroll
        for (int w = 0; w < BLK / 64; ++w) s += red[w];
        out[0] = (float)s;
    }
}

extern "C" void kernel_launch(void* const* d_in, const int* in_sizes, int n_in,
                              void* d_out, int out_size, void* d_ws, size_t ws_size,
                              hipStream_t stream) {
    const float* x = (const float*)d_in[0];
    // d_in[1] = cond (unused), d_in[2] = time (gives B)
    const int B = in_sizes[2];
    const int ntasks = B * TASKS_PER_B;

    int nblocks = (ntasks + BLK - 1) / BLK;   // 416 for B=4096
    const int max_blocks_ws = (int)(ws_size / sizeof(double));
    if (nblocks > max_blocks_ws) nblocks = max_blocks_ws > 0 ? max_blocks_ws : 1;

    double* partial = (double*)d_ws;
    float* out = (float*)d_out;

    cost_partial_kernel<<<nblocks, BLK, 0, stream>>>(x, partial, ntasks);
    cost_final_kernel<<<1, BLK, 0, stream>>>(partial, nblocks, out);
}